// Round 19
// baseline (98.590 us; speedup 1.0000x reference)
//
#include <hip/hip_runtime.h>
#include <math.h>

// Problem constants (x: (5,1,256,64,64) f32)
constexpr int NIMG = 5;
constexpr int CCH  = 256;   // channels (both c and d)
constexpr int HWP  = 4096;  // H*W
constexpr int PT   = CCH * HWP;  // elems per image = 1048576

// GEMM tiling (unfused, per image): 64 d x 128 p per block, BK=16, 2-phase
// double buffer, micro-tile 4d x 8p dual-acc = 64 acc regs, (256,2) cap 128.
// Per wave-cc LDS: 2xb128 x + b128 w1 + b128 w2 = 4 reads (48 cyc)
// -> floor 51 us (fused structure's floor is 65 us; R1 precedent shows this
// staging style attains its floor at ~10 waves/CU; here 2.5 blk/CU = 10 waves).
constexpr int BD = 64;
constexpr int BP = 128;
constexpr int BK = 16;
constexpr int NSTEP = CCH / BK;   // 16

// Async global->LDS, 16B/lane. LDS dest is wave-uniform base; HW adds lane*16.
__device__ __forceinline__ void gload16(const float* g, float* l) {
    __builtin_amdgcn_global_load_lds(
        (const __attribute__((address_space(1))) unsigned int*)g,
        (__attribute__((address_space(3))) unsigned int*)l, 16, 0, 0);
}

// -----------------------------------------------------------------------------
// Kernel 1 (per image n = blockIdx.z):
//   s[n,d,p]  = sum_c x[n,c,p]*(W1+W2)[c,d]   (wsa = w1+w2 per cc, in-loop —
//   v2[n,d,p] = sum_c x[n,c,p]*W2[c,d]         identical fp32 chain as R13)
// Staging: R13-proven pattern only — gload16, 2-phase &1 double buffer,
// counted vmcnt. 16 uniform-dest 1KB chunks/step, 4 per wave -> vmcnt(4).
// -----------------------------------------------------------------------------
__global__ __launch_bounds__(256, 2) void gemm_sv(
    const float* __restrict__ x, const float* __restrict__ w,
    float* __restrict__ s_out, float* __restrict__ v_out)
{
    const int t  = threadIdx.x;
    const int tp = t & 15;   // p-frag: cols tp*4..+3 and 64+tp*4..+3
    const int td = t >> 4;   // d-frag: rows td*4..+3
    const int p0 = blockIdx.x * BP;
    const int d0 = blockIdx.y * BD;
    const int n  = blockIdx.z;
    const float* xn = x + (size_t)n * PT;

    __shared__ float xs [2][BK][BP];  // 2 x 8 KB
    __shared__ float w1s[2][BK][BD];  // 2 x 4 KB
    __shared__ float w2s[2][BK][BD];  // 2 x 4 KB

    float acc_s[4][8] = {};
    float acc_2[4][8] = {};

    const int wv = t >> 6, l = t & 63;
    const int xr = l >> 5, xc = (l & 31) * 4;  // x chunk: 2 rows x 128 floats
    const int wr = l >> 4, wc = (l & 15) * 4;  // w chunk: 4 rows x 64 floats

    // Stage one K-step (c0) into buffer b. 4 gload16 per wave, uniform dests:
    //   x chunks wv and wv+4 (2 rows each), w1 chunk wv, w2 chunk wv (4 rows).
    auto stage = [&](int b, int c0) {
        #pragma unroll
        for (int k = 0; k < 2; ++k) {
            const int r0 = (wv + k * 4) * 2;
            gload16(&xn[(size_t)(c0 + r0 + xr) * HWP + p0 + xc], &xs[b][r0][0]);
        }
        gload16(&w[(size_t)(c0 + wv * 4 + wr) * CCH + d0 + wc],       &w1s[b][wv * 4][0]);
        gload16(&w[(size_t)(256 + c0 + wv * 4 + wr) * CCH + d0 + wc], &w2s[b][wv * 4][0]);
    };

    stage(0, 0);

    for (int st = 0; st < NSTEP; ++st) {
        const int cur = st & 1;
        if (st + 1 < NSTEP) {
            stage(cur ^ 1, (st + 1) * BK);
            asm volatile("s_waitcnt vmcnt(4)" ::: "memory");  // step st's loads done
        } else {
            asm volatile("s_waitcnt vmcnt(0)" ::: "memory");
        }
        __builtin_amdgcn_s_barrier();   // buffer cur fully staged (all waves)

        #pragma unroll
        for (int cc = 0; cc < BK; ++cc) {
            const float4 w1v = *reinterpret_cast<const float4*>(&w1s[cur][cc][td * 4]);
            const float4 w2v = *reinterpret_cast<const float4*>(&w2s[cur][cc][td * 4]);
            const float4 xv0 = *reinterpret_cast<const float4*>(&xs[cur][cc][tp * 4]);
            const float4 xv1 = *reinterpret_cast<const float4*>(&xs[cur][cc][64 + tp * 4]);
            const float xa [8] = {xv0.x, xv0.y, xv0.z, xv0.w,
                                  xv1.x, xv1.y, xv1.z, xv1.w};
            const float w2a[4] = {w2v.x, w2v.y, w2v.z, w2v.w};
            const float wsa[4] = {w1v.x + w2v.x, w1v.y + w2v.y,
                                  w1v.z + w2v.z, w1v.w + w2v.w};
            #pragma unroll
            for (int i = 0; i < 4; ++i) {
                #pragma unroll
                for (int j = 0; j < 8; ++j) {
                    acc_s[i][j] = fmaf(wsa[i], xa[j], acc_s[i][j]);
                    acc_2[i][j] = fmaf(w2a[i], xa[j], acc_2[i][j]);
                }
            }
        }
        __builtin_amdgcn_s_barrier();   // compute done before re-staging cur^1
    }

    // epilogue: store raw s and v2 (u formed in edge kernel)
    #pragma unroll
    for (int i = 0; i < 4; ++i) {
        const size_t base = (size_t)(d0 + td * 4 + i) * HWP + p0 + tp * 4;
        const float4 s0 = {acc_s[i][0], acc_s[i][1], acc_s[i][2], acc_s[i][3]};
        const float4 s1 = {acc_s[i][4], acc_s[i][5], acc_s[i][6], acc_s[i][7]};
        const float4 v0 = {acc_2[i][0], acc_2[i][1], acc_2[i][2], acc_2[i][3]};
        const float4 v1 = {acc_2[i][4], acc_2[i][5], acc_2[i][6], acc_2[i][7]};
        *reinterpret_cast<float4*>(&s_out[(size_t)n * PT + base])      = s0;
        *reinterpret_cast<float4*>(&s_out[(size_t)n * PT + base + 64]) = s1;
        *reinterpret_cast<float4*>(&v_out[(size_t)n * PT + base])      = v0;
        *reinterpret_cast<float4*>(&v_out[(size_t)n * PT + base + 64]) = v1;
    }
}

// -----------------------------------------------------------------------------
// Kernel 2 (verbatim from the R10 PASSING version): per-pixel edges.
// u[n] = (x[n] - s[n]) - b[d]; v[n] = v2[n]; e[i][j]=|u[j]-v[i]|;
// row-norm threshold; out[i] = sum_j kept_e * x[j]. Bit-identical math.
// -----------------------------------------------------------------------------
__global__ __launch_bounds__(256) void edge_out(
    const float* __restrict__ x, const float* __restrict__ s,
    const float* __restrict__ v2, const float* __restrict__ bias,
    float* __restrict__ out)
{
    const size_t p = ((size_t)blockIdx.x * blockDim.x + threadIdx.x) * 4;
    if (p >= (size_t)PT) return;
    const float bd = bias[p >> 12];   // d = p / 4096 (same for all 4 pixels)

    float xa[NIMG][4], ua[NIMG][4], va[NIMG][4];
    #pragma unroll
    for (int n2 = 0; n2 < NIMG; ++n2) {
        const float4 xv = *reinterpret_cast<const float4*>(&x [(size_t)n2 * PT + p]);
        const float4 sv = *reinterpret_cast<const float4*>(&s [(size_t)n2 * PT + p]);
        const float4 vv = *reinterpret_cast<const float4*>(&v2[(size_t)n2 * PT + p]);
        const float xt[4] = {xv.x, xv.y, xv.z, xv.w};
        const float st[4] = {sv.x, sv.y, sv.z, sv.w};
        const float vt[4] = {vv.x, vv.y, vv.z, vv.w};
        #pragma unroll
        for (int q = 0; q < 4; ++q) {
            xa[n2][q] = xt[q];
            ua[n2][q] = (xt[q] - st[q]) - bd;
            va[n2][q] = vt[q];
        }
    }

    float oacc[NIMG][4];
    #pragma unroll
    for (int q = 0; q < 4; ++q) {
        #pragma unroll
        for (int i = 0; i < NIMG; ++i) {
            float e[NIMG];
            float sumsq = 0.0f;
            #pragma unroll
            for (int j = 0; j < NIMG; ++j) {
                e[j] = fabsf(ua[j][q] - va[i][q]);
                sumsq = fmaf(e[j], e[j], sumsq);
            }
            const float m = fmaxf(sqrtf(sumsq), 1e-12f);
            float h = 0.0f;
            #pragma unroll
            for (int j = 0; j < NIMG; ++j) {
                const float en = e[j] / m;
                if (en > 0.35f) h = fmaf(e[j], xa[j][q], h);
            }
            oacc[i][q] = h;
        }
    }

    #pragma unroll
    for (int i = 0; i < NIMG; ++i) {
        const float4 ov = {oacc[i][0], oacc[i][1], oacc[i][2], oacc[i][3]};
        *reinterpret_cast<float4*>(&out[(size_t)i * PT + p]) = ov;
    }
}

extern "C" void kernel_launch(void* const* d_in, const int* in_sizes, int n_in,
                              void* d_out, int out_size, void* d_ws, size_t ws_size,
                              hipStream_t stream) {
    const float* x    = (const float*)d_in[0];
    const float* w    = (const float*)d_in[1];
    const float* bias = (const float*)d_in[2];
    float* out = (float*)d_out;

    float* s  = (float*)d_ws;                      // 20 MB
    float* v2 = s + (size_t)NIMG * PT;             // 20 MB

    dim3 g1(HWP / BP, CCH / BD, NIMG);             // 32 x 4 x 5 = 640 blocks
    gemm_sv<<<g1, 256, 0, stream>>>(x, w, s, v2);

    const int n4 = PT / 4;                         // 262144 pixel-quads
    edge_out<<<(n4 + 255) / 256, 256, 0, stream>>>(x, s, v2, bias, out);
}

// Round 20
// 82.499 us; speedup vs baseline: 1.1950x; 1.1950x over previous
//
#include <hip/hip_runtime.h>
#include <math.h>

// Problem constants (x: (5,1,256,64,64) f32)
constexpr int NIMG = 5;
constexpr int CCH  = 256;   // channels (both c and d)
constexpr int HWP  = 4096;  // H*W
constexpr int PT   = CCH * HWP;  // elems per image = 1048576

// Tiling: 32 d x 64 p per block, K-step 16, double-buffered, n-loop in block.
constexpr int BD = 32;
constexpr int BP = 64;
constexpr int BK = 16;
constexpr int NSTEP = CCH / BK;   // 16

// Async global->LDS, 16B/lane. LDS dest is wave-uniform base; HW adds lane*16.
__device__ __forceinline__ void gload16(const float* g, float* l) {
    __builtin_amdgcn_global_load_lds(
        (const __attribute__((address_space(1))) unsigned int*)g,
        (__attribute__((address_space(3))) unsigned int*)l, 16, 0, 0);
}

// -----------------------------------------------------------------------------
// Fully fused: per block (d0,p0), all 5 images; 2-phase double-buffered K-loop
// with counted vmcnt (loads in flight across barriers — no vmcnt(0) drain
// mid-loop). Session-best structure (82.2-82.7 us, reproduced 3x).
//   acc_s[n] = sum_c x[n,c,p]*(W1+W2)[c,d],  acc_2[n] = sum_c x[n,c,p]*W2[c,d]
//   u = x - acc_s - b ; v = acc_2 ; e=|u[j]-v[i]| ; thresholded weighted sum.
// -----------------------------------------------------------------------------
__global__ __launch_bounds__(256, 2) void fused_all(
    const float* __restrict__ x, const float* __restrict__ w,
    const float* __restrict__ bias, float* __restrict__ out)
{
    const int t  = threadIdx.x;
    const int tp = t & 15;   // p-frag: cols p0 + tp*4 .. +3
    const int td = t >> 4;   // d-frag: rows d0 + td*2, td*2+1
    const int p0 = blockIdx.x * BP;
    const int d0 = blockIdx.y * BD;

    __shared__ float xs [2][NIMG][BK][BP];  // 2 x 20 KB
    __shared__ float w1s[2][BK][BD];        // 2 x 2 KB
    __shared__ float w2s[2][BK][BD];        // 2 x 2 KB

    float acc_s[NIMG][2][4] = {};
    float acc_2[NIMG][2][4] = {};

    const int wv = t >> 6, l = t & 63;
    const int xr = l >> 4, xc = (l & 15) * 4;  // x chunk: 4 rows x 64 floats
    const int wr = l >> 3, wc = (l & 7) * 4;   // w chunk: 8 rows x 32 floats

    // Stage one K-step (c0) into buffer b. 6 gload16 per wave, uniform:
    //  - 5 x-chunks: global chunk id g = wv + 4s, s=0..4 -> n=g>>2, k=g&3
    //  - 1 w-chunk : wv<2 -> w1 chunk wv ; else w2 chunk wv-2
    auto stage = [&](int b, int c0) {
        #pragma unroll
        for (int s = 0; s < NIMG; ++s) {
            const int g = wv + 4 * s;
            const int n = g >> 2, k = g & 3;
            gload16(&x[(size_t)n * PT + (size_t)(c0 + k * 4 + xr) * HWP + p0 + xc],
                    &xs[b][n][k * 4][0]);
        }
        if (wv < 2) {
            gload16(&w[(size_t)(c0 + wv * 8 + wr) * CCH + d0 + wc],
                    &w1s[b][wv * 8][0]);
        } else {
            gload16(&w[(size_t)(256 + c0 + (wv - 2) * 8 + wr) * CCH + d0 + wc],
                    &w2s[b][(wv - 2) * 8][0]);
        }
    };

    stage(0, 0);

    for (int st = 0; st < NSTEP; ++st) {
        const int cur = st & 1;
        if (st + 1 < NSTEP) {
            stage(cur ^ 1, (st + 1) * BK);
            asm volatile("s_waitcnt vmcnt(6)" ::: "memory");  // step st's loads done
        } else {
            asm volatile("s_waitcnt vmcnt(0)" ::: "memory");
        }
        __builtin_amdgcn_s_barrier();   // buffer cur fully staged (all waves)

        #pragma unroll
        for (int cc = 0; cc < BK; ++cc) {
            const float2 w1v = *reinterpret_cast<const float2*>(&w1s[cur][cc][td * 2]);
            const float2 w2v = *reinterpret_cast<const float2*>(&w2s[cur][cc][td * 2]);
            const float w2a[2] = {w2v.x, w2v.y};
            const float wsa[2] = {w1v.x + w2v.x, w1v.y + w2v.y};
            #pragma unroll
            for (int n = 0; n < NIMG; ++n) {
                const float4 xv = *reinterpret_cast<const float4*>(&xs[cur][n][cc][tp * 4]);
                const float xb[4] = {xv.x, xv.y, xv.z, xv.w};
                #pragma unroll
                for (int i = 0; i < 2; ++i) {
                    #pragma unroll
                    for (int j = 0; j < 4; ++j) {
                        acc_s[n][i][j] = fmaf(wsa[i], xb[j], acc_s[n][i][j]);
                        acc_2[n][i][j] = fmaf(w2a[i], xb[j], acc_2[n][i][j]);
                    }
                }
            }
        }
        __builtin_amdgcn_s_barrier();   // compute done before re-staging cur^1
    }

    // ---------------- fused epilogue: edges + threshold + reduce ----------------
    #pragma unroll
    for (int r = 0; r < 2; ++r) {
        const int d = d0 + td * 2 + r;
        const float bd = bias[d];
        const size_t base = (size_t)d * HWP + p0 + tp * 4;

        float xa[NIMG][4], ua[NIMG][4], va[NIMG][4];
        #pragma unroll
        for (int n = 0; n < NIMG; ++n) {
            const float4 xv = *reinterpret_cast<const float4*>(&x[(size_t)n * PT + base]);
            const float xt[4] = {xv.x, xv.y, xv.z, xv.w};
            #pragma unroll
            for (int q = 0; q < 4; ++q) {
                xa[n][q] = xt[q];
                ua[n][q] = xt[q] - acc_s[n][r][q] - bd;
                va[n][q] = acc_2[n][r][q];
            }
        }

        #pragma unroll
        for (int i = 0; i < NIMG; ++i) {
            float ho[4];
            #pragma unroll
            for (int q = 0; q < 4; ++q) {
                float e[NIMG];
                float sumsq = 0.0f;
                #pragma unroll
                for (int j = 0; j < NIMG; ++j) {
                    e[j] = fabsf(ua[j][q] - va[i][q]);
                    sumsq = fmaf(e[j], e[j], sumsq);
                }
                const float m = fmaxf(sqrtf(sumsq), 1e-12f);
                float h = 0.0f;
                #pragma unroll
                for (int j = 0; j < NIMG; ++j) {
                    const float en = e[j] / m;
                    if (en > 0.35f) h = fmaf(e[j], xa[j][q], h);
                }
                ho[q] = h;
            }
            const float2 ov0 = {ho[0], ho[1]};
            const float2 ov1 = {ho[2], ho[3]};
            *reinterpret_cast<float2*>(&out[(size_t)i * PT + base])     = ov0;
            *reinterpret_cast<float2*>(&out[(size_t)i * PT + base + 2]) = ov1;
        }
    }
}

extern "C" void kernel_launch(void* const* d_in, const int* in_sizes, int n_in,
                              void* d_out, int out_size, void* d_ws, size_t ws_size,
                              hipStream_t stream) {
    const float* x    = (const float*)d_in[0];
    const float* w    = (const float*)d_in[1];
    const float* bias = (const float*)d_in[2];
    float* out = (float*)d_out;

    dim3 g(HWP / BP, CCH / BD);   // 64 x 8 = 512 blocks
    fused_all<<<g, 256, 0, stream>>>(x, w, bias, out);
}